// Round 8
// baseline (107.135 us; speedup 1.0000x reference)
//
#include <hip/hip_runtime.h>

#define HH 256
#define WW 256
#define HWSZ (HH*WW)
#define CC 64
#define GG 4
#define GC 16
#define KK 3
#define PP 9
#define NB 2
#define NBG (NB*GG)            // 8 (b,g) slices
#define NBLK_RP (NBG*HH)       // 2048 repack blocks
#define NBLK_MAIN (NBG*1024)   // 8192 main blocks (64 pixels x 4 lanes each)

typedef float f32x4 __attribute__((ext_vector_type(4)));

// ---------- Kernel 1: planar -> channels-last repack (per (b,g): [y][x][16]) ----------
// img is read once -> non-temporal (don't pollute L2); pk stores stay normal so
// the packed slice is L2-resident on the XCD that will gather from it.
__global__ __launch_bounds__(256) void repack_kernel(
    const float* __restrict__ img, float* __restrict__ pk)
{
    int bid = blockIdx.x;
    int y  = bid & (HH - 1);
    int bg = bid >> 8;
    int g  = bg & (GG - 1);
    int b  = bg >> 2;
    int x  = threadIdx.x;

    const float* src = img + (size_t)(b*CC + g*GC) * HWSZ + y*WW + x;
    float v[GC];
#pragma unroll
    for (int c = 0; c < GC; ++c) v[c] = __builtin_nontemporal_load(&src[c*HWSZ]);

    float4* dst = (float4*)(pk + ((size_t)bg*HWSZ + y*WW + x) * GC);
#pragma unroll
    for (int q = 0; q < 4; ++q)
        dst[q] = make_float4(v[4*q], v[4*q+1], v[4*q+2], v[4*q+3]);
}

// ---------- Kernel 2: cooperative filter, asm-load pipeline w/ counted vmcnt ----------
// 4 lanes per pixel; lane q owns channels [4q,4q+4). Each gather instr reads
// 16 full 64B lines (minimum). 3-tap rotating buffer, counted vmcnt(8).
// Streaming accesses (params, output) are non-temporal so the 4MB packed slice
// stays L2-resident. NOTE: launch_bounds must stay (256,4): the asm-load
// destinations (vv, 48 VGPRs) must never be moved/spilled while in flight —
// a 64-VGPR budget at (256,8) made the allocator copy them before the waitcnt
// (round-7 failure, absmax 28).
__global__ __launch_bounds__(256, 4) void misc_filter_coop(
    const float* __restrict__ pk,
    const float* __restrict__ kv,
    const float* __restrict__ kh,
    const float* __restrict__ off,
    const float* __restrict__ wgt,
    float* __restrict__ out)
{
    // XCD swizzle: 8192 blocks / 8 XCDs -> each XCD exactly one (b,g);
    // its 4MB packed slice lives in that XCD's L2 (seeded by repack).
    int phys = blockIdx.x;
    int logical = (phys & 7) * (NBLK_MAIN / 8) + (phys >> 3);
    int bg  = logical >> 10;          // 1024 blocks per (b,g)
    int blk = logical & 1023;
    int g   = bg & (GG - 1);
    int b   = bg >> 2;

    int t  = threadIdx.x;
    int q  = t & 3;                   // channel quad
    int pi = t >> 2;                  // pixel within block [0,64)
    int pixel = blk * 64 + pi;
    int y = pixel >> 8;
    int x = pixel & (WW - 1);

    const float* pkb = pk + (size_t)bg * HWSZ * GC;   // wave-uniform SGPR base
    const float* offp = off + (size_t)(b*GG*PP*2 + g*PP*2) * HWSZ + pixel;
    const float* wgtp = wgt + (size_t)(b*GG*PP   + g*PP  ) * HWSZ + pixel;
    const float* khp  = kh  + (size_t)(b*GG*KK   + g*KK  ) * HWSZ + pixel;
    const float* kvp  = kv  + (size_t)(b*KK) * HWSZ + pixel;

    // ---- hoisted parameter loads (read-once streams: non-temporal) ----
    float oxr[PP], oyr[PP], wpall[PP];
#pragma unroll
    for (int p = 0; p < PP; ++p) {
        oxr[p]   = __builtin_nontemporal_load(&offp[(2*p  )*HWSZ]);
        oyr[p]   = __builtin_nontemporal_load(&offp[(2*p+1)*HWSZ]);
        wpall[p] = __builtin_nontemporal_load(&wgtp[p*HWSZ]);
    }
    {
        float khr[KK], kvr[KK];
#pragma unroll
        for (int i = 0; i < KK; ++i) {
            khr[i] = __builtin_nontemporal_load(&khp[i*HWSZ]);
            kvr[i] = __builtin_nontemporal_load(&kvp[i*HWSZ]);
        }
#pragma unroll
        for (int p = 0; p < PP; ++p) wpall[p] *= khr[p/KK] * kvr[p%KK];
    }

    // Drain ALL compiler loads before the asm region so the compiler's vmcnt
    // bookkeeping (which cannot see our asm loads) stays correct & harmless.
    asm volatile("s_waitcnt vmcnt(0)" ::: "memory");
    __builtin_amdgcn_sched_barrier(0);

    float acc0 = 0.f, acc1 = 0.f, acc2 = 0.f, acc3 = 0.f;
    const unsigned qoffb = (unsigned)q * 16u;   // byte offset of lane's quadrant
    const float xf = (float)(x - 1);
    const float yf = (float)(y - 1);

    float  w4[3][4];      // folded corner weights, 3-tap rotation
    f32x4  vv[3][4];      // in-flight corner vectors, 3-tap rotation

#define GLOAD(dst, boff) \
    asm volatile("global_load_dwordx4 %0, %1, %2" \
                 : "=v"(dst) : "v"(boff), "s"(pkb) : "memory")

#define WAITV(N) do { \
    asm volatile("s_waitcnt vmcnt(" #N ")" ::: "memory"); \
    __builtin_amdgcn_sched_barrier(0); } while (0)

#define TAP_MATH_LOAD(p) do {                                                   \
    const int kx_ = (p) / KK, ky_ = (p) % KK, bi_ = (p) % 3;                    \
    float wp_ = wpall[p];                                                       \
    float ux_ = xf + (float)kx_ + oxr[p];                                       \
    float uy_ = yf + (float)ky_ + oyr[p];                                       \
    float fx_ = floorf(ux_), fy_ = floorf(uy_);                                 \
    float wx_ = ux_ - fx_,   wy_ = uy_ - fy_;                                   \
    int x0_ = (int)fx_, y0_ = (int)fy_;                                         \
    int x1_ = x0_ + 1,  y1_ = y0_ + 1;                                          \
    bool vx0_ = (unsigned)x0_ < (unsigned)WW;                                   \
    bool vx1_ = (unsigned)x1_ < (unsigned)WW;                                   \
    bool vy0_ = (unsigned)y0_ < (unsigned)HH;                                   \
    bool vy1_ = (unsigned)y1_ < (unsigned)HH;                                   \
    float w00_ = (1.f-wx_)*(1.f-wy_)*wp_; if (!(vx0_ && vy0_)) w00_ = 0.f;      \
    float w01_ =      wx_ *(1.f-wy_)*wp_; if (!(vx1_ && vy0_)) w01_ = 0.f;      \
    float w10_ = (1.f-wx_)*     wy_ *wp_; if (!(vx0_ && vy1_)) w10_ = 0.f;      \
    float w11_ =      wx_ *     wy_ *wp_; if (!(vx1_ && vy1_)) w11_ = 0.f;      \
    int x0c_ = min(max(x0_, 0), WW-1), x1c_ = min(max(x1_, 0), WW-1);           \
    int y0c_ = min(max(y0_, 0), HH-1), y1c_ = min(max(y1_, 0), HH-1);           \
    w4[bi_][0] = w00_; w4[bi_][1] = w01_; w4[bi_][2] = w10_; w4[bi_][3] = w11_; \
    unsigned o00_ = (unsigned)((y0c_*WW + x0c_)*(GC*4)) + qoffb;                \
    unsigned o01_ = (unsigned)((y0c_*WW + x1c_)*(GC*4)) + qoffb;                \
    unsigned o10_ = (unsigned)((y1c_*WW + x0c_)*(GC*4)) + qoffb;                \
    unsigned o11_ = (unsigned)((y1c_*WW + x1c_)*(GC*4)) + qoffb;                \
    GLOAD(vv[bi_][0], o00_);                                                    \
    GLOAD(vv[bi_][1], o01_);                                                    \
    GLOAD(vv[bi_][2], o10_);                                                    \
    GLOAD(vv[bi_][3], o11_);                                                    \
} while (0)

#define TAP_FMA(p) do {                                                         \
    const int bi_ = (p) % 3;                                                    \
    acc0 = fmaf(w4[bi_][0], vv[bi_][0][0], acc0);                               \
    acc1 = fmaf(w4[bi_][0], vv[bi_][0][1], acc1);                               \
    acc2 = fmaf(w4[bi_][0], vv[bi_][0][2], acc2);                               \
    acc3 = fmaf(w4[bi_][0], vv[bi_][0][3], acc3);                               \
    acc0 = fmaf(w4[bi_][1], vv[bi_][1][0], acc0);                               \
    acc1 = fmaf(w4[bi_][1], vv[bi_][1][1], acc1);                               \
    acc2 = fmaf(w4[bi_][1], vv[bi_][1][2], acc2);                               \
    acc3 = fmaf(w4[bi_][1], vv[bi_][1][3], acc3);                               \
    acc0 = fmaf(w4[bi_][2], vv[bi_][2][0], acc0);                               \
    acc1 = fmaf(w4[bi_][2], vv[bi_][2][1], acc1);                               \
    acc2 = fmaf(w4[bi_][2], vv[bi_][2][2], acc2);                               \
    acc3 = fmaf(w4[bi_][2], vv[bi_][2][3], acc3);                               \
    acc0 = fmaf(w4[bi_][3], vv[bi_][3][0], acc0);                               \
    acc1 = fmaf(w4[bi_][3], vv[bi_][3][1], acc1);                               \
    acc2 = fmaf(w4[bi_][3], vv[bi_][3][2], acc2);                               \
    acc3 = fmaf(w4[bi_][3], vv[bi_][3][3], acc3);                               \
} while (0)

    TAP_MATH_LOAD(0);
    TAP_MATH_LOAD(1);
    TAP_MATH_LOAD(2);   WAITV(8); TAP_FMA(0);
    TAP_MATH_LOAD(3);   WAITV(8); TAP_FMA(1);
    TAP_MATH_LOAD(4);   WAITV(8); TAP_FMA(2);
    TAP_MATH_LOAD(5);   WAITV(8); TAP_FMA(3);
    TAP_MATH_LOAD(6);   WAITV(8); TAP_FMA(4);
    TAP_MATH_LOAD(7);   WAITV(8); TAP_FMA(5);
    TAP_MATH_LOAD(8);   WAITV(8); TAP_FMA(6);
    WAITV(4); TAP_FMA(7);
    WAITV(0); TAP_FMA(8);

#undef GLOAD
#undef WAITV
#undef TAP_MATH_LOAD
#undef TAP_FMA

    // planar output: pure stream -> non-temporal, don't evict the packed slice
    float* outp = out + (size_t)(b*CC + g*GC + q*4) * HWSZ + pixel;
    __builtin_nontemporal_store(acc0, &outp[0*HWSZ]);
    __builtin_nontemporal_store(acc1, &outp[1*HWSZ]);
    __builtin_nontemporal_store(acc2, &outp[2*HWSZ]);
    __builtin_nontemporal_store(acc3, &outp[3*HWSZ]);
}

// ---------- Fallback: direct planar kernel (if ws too small) ----------
__global__ __launch_bounds__(256) void misc_filter_direct(
    const float* __restrict__ img,
    const float* __restrict__ kv,
    const float* __restrict__ kh,
    const float* __restrict__ off,
    const float* __restrict__ wgt,
    float* __restrict__ out)
{
    int phys = blockIdx.x;
    int logical = (phys & 7) * (NBLK_RP / 8) + (phys >> 3);
    int y  = logical & (HH - 1);
    int bg = logical >> 8;
    int g  = bg & (GG - 1);
    int b  = bg >> 2;
    int x  = threadIdx.x;

    const float* imgp = img + (size_t)(b*CC + g*GC) * HWSZ;
    int pix = y*WW + x;
    const float* offp = off + (size_t)(b*GG*PP*2 + g*PP*2) * HWSZ + pix;
    const float* wgtp = wgt + (size_t)(b*GG*PP   + g*PP  ) * HWSZ + pix;
    const float* khp  = kh  + (size_t)(b*GG*KK   + g*KK  ) * HWSZ + pix;
    const float* kvp  = kv  + (size_t)(b*KK) * HWSZ + pix;

    float khr[KK], kvr[KK];
#pragma unroll
    for (int i = 0; i < KK; ++i) { khr[i] = khp[i*HWSZ]; kvr[i] = kvp[i*HWSZ]; }
    float acc[GC];
#pragma unroll
    for (int c = 0; c < GC; ++c) acc[c] = 0.f;

#pragma unroll
    for (int p = 0; p < PP; ++p) {
        const int kx = p / KK, ky = p % KK;
        float ox = offp[(2*p  )*HWSZ];
        float oy = offp[(2*p+1)*HWSZ];
        float wp = wgtp[p*HWSZ] * khr[kx] * kvr[ky];
        float ux = (float)(x + kx - 1) + ox;
        float uy = (float)(y + ky - 1) + oy;
        float fx = floorf(ux), fy = floorf(uy);
        float wx = ux - fx,    wy = uy - fy;
        int x0 = (int)fx, y0 = (int)fy;
        int x1 = x0 + 1,  y1 = y0 + 1;
        bool vx0 = (unsigned)x0 < (unsigned)WW;
        bool vx1 = (unsigned)x1 < (unsigned)WW;
        bool vy0 = (unsigned)y0 < (unsigned)HH;
        bool vy1 = (unsigned)y1 < (unsigned)HH;
        float w00 = (1.f-wx)*(1.f-wy)*wp; if (!(vx0 && vy0)) w00 = 0.f;
        float w01 =      wx *(1.f-wy)*wp; if (!(vx1 && vy0)) w01 = 0.f;
        float w10 = (1.f-wx)*     wy *wp; if (!(vx0 && vy1)) w10 = 0.f;
        float w11 =      wx *     wy *wp; if (!(vx1 && vy1)) w11 = 0.f;
        int x0c = min(max(x0, 0), WW-1), x1c = min(max(x1, 0), WW-1);
        int y0c = min(max(y0, 0), HH-1), y1c = min(max(y1, 0), HH-1);
        int i00 = y0c*WW + x0c, i01 = y0c*WW + x1c;
        int i10 = y1c*WW + x0c, i11 = y1c*WW + x1c;
#pragma unroll
        for (int c = 0; c < GC; ++c) {
            const float* pl = imgp + c*HWSZ;
            acc[c] = fmaf(w00, pl[i00], acc[c]);
            acc[c] = fmaf(w01, pl[i01], acc[c]);
            acc[c] = fmaf(w10, pl[i10], acc[c]);
            acc[c] = fmaf(w11, pl[i11], acc[c]);
        }
    }
    float* outp = out + (size_t)(b*CC + g*GC) * HWSZ + pix;
#pragma unroll
    for (int c = 0; c < GC; ++c) outp[c*HWSZ] = acc[c];
}

extern "C" void kernel_launch(void* const* d_in, const int* in_sizes, int n_in,
                              void* d_out, int out_size, void* d_ws, size_t ws_size,
                              hipStream_t stream) {
    const float* img = (const float*)d_in[0];
    const float* kv  = (const float*)d_in[1];
    const float* kh  = (const float*)d_in[2];
    const float* off = (const float*)d_in[3];
    const float* wgt = (const float*)d_in[4];
    float* out = (float*)d_out;

    const size_t need = (size_t)NBG * HWSZ * GC * sizeof(float);  // 33.5 MB
    if (ws_size >= need) {
        float* pk = (float*)d_ws;
        repack_kernel<<<dim3(NBLK_RP), dim3(WW), 0, stream>>>(img, pk);
        misc_filter_coop<<<dim3(NBLK_MAIN), dim3(256), 0, stream>>>(pk, kv, kh, off, wgt, out);
    } else {
        misc_filter_direct<<<dim3(NBLK_RP), dim3(WW), 0, stream>>>(img, kv, kh, off, wgt, out);
    }
}

// Round 9
// 69.055 us; speedup vs baseline: 1.5514x; 1.5514x over previous
//
#include <hip/hip_runtime.h>

#define HH 256
#define WW 256
#define HWSZ (HH*WW)
#define CC 64
#define GG 4
#define GC 16
#define KK 3
#define PP 9
#define NB 2
#define NBG (NB*GG)            // 8 (b,g) slices
#define NBLK_RP (NBG*HH)       // 2048 repack blocks
#define NBLK_MAIN (NBG*1024)   // 8192 main blocks (64 pixels x 4 lanes each)

typedef float f32x4 __attribute__((ext_vector_type(4)));

// ---------- Kernel 1: planar -> channels-last repack (per (b,g): [y][x][16]) ----------
__global__ __launch_bounds__(256) void repack_kernel(
    const float* __restrict__ img, float* __restrict__ pk)
{
    int bid = blockIdx.x;
    int y  = bid & (HH - 1);
    int bg = bid >> 8;
    int g  = bg & (GG - 1);
    int b  = bg >> 2;
    int x  = threadIdx.x;

    const float* src = img + (size_t)(b*CC + g*GC) * HWSZ + y*WW + x;
    float v[GC];
#pragma unroll
    for (int c = 0; c < GC; ++c) v[c] = src[c*HWSZ];

    float4* dst = (float4*)(pk + ((size_t)bg*HWSZ + y*WW + x) * GC);
#pragma unroll
    for (int q = 0; q < 4; ++q)
        dst[q] = make_float4(v[4*q], v[4*q+1], v[4*q+2], v[4*q+3]);
}

// ---------- Kernel 2: LDS-dedup'd math + asm gather pipeline ----------
// Phase 1: 576 (pixel,tap) jobs over 256 threads compute folded weights +
//          clamped byte-offsets ONCE per pixel (was 4x replicated) -> LDS.
// Phase 2: 4 lanes/pixel, 3-tap rotating asm pipeline, counted vmcnt(8).
// launch_bounds must stay (256,4): asm-load dest regs (vv, 48 VGPR) must not
// be moved/spilled while in flight (round-7 failure at (256,8)).
__global__ __launch_bounds__(256, 4) void misc_filter_coop(
    const float* __restrict__ pk,
    const float* __restrict__ kv,
    const float* __restrict__ kh,
    const float* __restrict__ off,
    const float* __restrict__ wgt,
    float* __restrict__ out)
{
    // XCD swizzle: 8192 blocks / 8 XCDs -> each XCD exactly one (b,g) slice.
    int phys = blockIdx.x;
    int logical = (phys & 7) * (NBLK_MAIN / 8) + (phys >> 3);
    int bg  = logical >> 10;          // 1024 blocks per (b,g)
    int blk = logical & 1023;
    int g   = bg & (GG - 1);
    int b   = bg >> 2;

    int t  = threadIdx.x;
    const int pixbase = blk * 64;

    __shared__ float Wlds[PP][64][4];   // folded corner weights
    __shared__ int   Olds[PP][64][4];   // corner byte offsets (pre-quadrant)

    const float* offb = off + (size_t)(b*GG*PP*2 + g*PP*2) * HWSZ + pixbase;
    const float* wgtb = wgt + (size_t)(b*GG*PP   + g*PP  ) * HWSZ + pixbase;
    const float* khb  = kh  + (size_t)(b*GG*KK   + g*KK  ) * HWSZ + pixbase;
    const float* kvb  = kv  + (size_t)(b*KK) * HWSZ + pixbase;

    // ---- Phase 1: per-(pixel,tap) math, computed once, shared via LDS ----
    // wave0: 3 jobs, waves1-3: 2 jobs (wave-uniform trip counts).
    for (int j = t; j < 64*PP; j += 256) {
        int px  = j & 63;
        int tap = j >> 6;
        int kx  = (tap * 11) >> 5;          // tap/3 for tap<9
        int ky  = tap - 3*kx;
        int pixel1 = pixbase + px;
        int yy = pixel1 >> 8;
        int xx = pixel1 & (WW - 1);

        float ox  = offb[(2*tap  )*HWSZ + px];
        float oy  = offb[(2*tap+1)*HWSZ + px];
        float wv  = wgtb[tap*HWSZ + px];
        float khv = khb[kx*HWSZ + px];
        float kvv = kvb[ky*HWSZ + px];
        float wp  = wv * (khv * kvv);

        float ux = (float)(xx + kx - 1) + ox;
        float uy = (float)(yy + ky - 1) + oy;
        float fx = floorf(ux), fy = floorf(uy);
        float wx = ux - fx,    wy = uy - fy;
        int x0 = (int)fx, y0 = (int)fy;
        int x1 = x0 + 1,  y1 = y0 + 1;
        bool vx0 = (unsigned)x0 < (unsigned)WW;
        bool vx1 = (unsigned)x1 < (unsigned)WW;
        bool vy0 = (unsigned)y0 < (unsigned)HH;
        bool vy1 = (unsigned)y1 < (unsigned)HH;
        float w00 = (1.f-wx)*(1.f-wy)*wp; if (!(vx0 && vy0)) w00 = 0.f;
        float w01 =      wx *(1.f-wy)*wp; if (!(vx1 && vy0)) w01 = 0.f;
        float w10 = (1.f-wx)*     wy *wp; if (!(vx0 && vy1)) w10 = 0.f;
        float w11 =      wx *     wy *wp; if (!(vx1 && vy1)) w11 = 0.f;
        int x0c = min(max(x0, 0), WW-1), x1c = min(max(x1, 0), WW-1);
        int y0c = min(max(y0, 0), HH-1), y1c = min(max(y1, 0), HH-1);

        *(float4*)&Wlds[tap][px][0] = make_float4(w00, w01, w10, w11);
        *(int4*)&Olds[tap][px][0]   = make_int4((y0c*WW + x0c)*(GC*4),
                                                (y0c*WW + x1c)*(GC*4),
                                                (y1c*WW + x0c)*(GC*4),
                                                (y1c*WW + x1c)*(GC*4));
    }
    __syncthreads();

    // ---- Phase 2: gather + FMA pipeline ----
    int q  = t & 3;                   // channel quad
    int pi = t >> 2;                  // pixel within block [0,64)
    int pixel = pixbase + pi;

    const float* pkb = pk + (size_t)bg * HWSZ * GC;   // wave-uniform SGPR base
    const unsigned qoffb = (unsigned)q * 16u;

    float acc0 = 0.f, acc1 = 0.f, acc2 = 0.f, acc3 = 0.f;
    f32x4 w4[3];          // folded weights, 3-tap rotation
    f32x4 vv[3][4];       // in-flight corner vectors, 3-tap rotation

#define GLOAD(dst, boff) \
    asm volatile("global_load_dwordx4 %0, %1, %2" \
                 : "=v"(dst) : "v"(boff), "s"(pkb) : "memory")

#define WAITV(N) do { \
    asm volatile("s_waitcnt vmcnt(" #N ")" ::: "memory"); \
    __builtin_amdgcn_sched_barrier(0); } while (0)

#define TAP_LOAD(p) do {                                                        \
    const int bi_ = (p) % 3;                                                    \
    f32x4 wv_ = *(const f32x4*)&Wlds[p][pi][0];                                 \
    int4  ov_ = *(const int4*)&Olds[p][pi][0];                                  \
    w4[bi_] = wv_;                                                              \
    GLOAD(vv[bi_][0], (unsigned)ov_.x + qoffb);                                 \
    GLOAD(vv[bi_][1], (unsigned)ov_.y + qoffb);                                 \
    GLOAD(vv[bi_][2], (unsigned)ov_.z + qoffb);                                 \
    GLOAD(vv[bi_][3], (unsigned)ov_.w + qoffb);                                 \
} while (0)

#define TAP_FMA(p) do {                                                         \
    const int bi_ = (p) % 3;                                                    \
    acc0 = fmaf(w4[bi_][0], vv[bi_][0][0], acc0);                               \
    acc1 = fmaf(w4[bi_][0], vv[bi_][0][1], acc1);                               \
    acc2 = fmaf(w4[bi_][0], vv[bi_][0][2], acc2);                               \
    acc3 = fmaf(w4[bi_][0], vv[bi_][0][3], acc3);                               \
    acc0 = fmaf(w4[bi_][1], vv[bi_][1][0], acc0);                               \
    acc1 = fmaf(w4[bi_][1], vv[bi_][1][1], acc1);                               \
    acc2 = fmaf(w4[bi_][1], vv[bi_][1][2], acc2);                               \
    acc3 = fmaf(w4[bi_][1], vv[bi_][1][3], acc3);                               \
    acc0 = fmaf(w4[bi_][2], vv[bi_][2][0], acc0);                               \
    acc1 = fmaf(w4[bi_][2], vv[bi_][2][1], acc1);                               \
    acc2 = fmaf(w4[bi_][2], vv[bi_][2][2], acc2);                               \
    acc3 = fmaf(w4[bi_][2], vv[bi_][2][3], acc3);                               \
    acc0 = fmaf(w4[bi_][3], vv[bi_][3][0], acc0);                               \
    acc1 = fmaf(w4[bi_][3], vv[bi_][3][1], acc1);                               \
    acc2 = fmaf(w4[bi_][3], vv[bi_][3][2], acc2);                               \
    acc3 = fmaf(w4[bi_][3], vv[bi_][3][3], acc3);                               \
} while (0)

    TAP_LOAD(0);
    TAP_LOAD(1);
    TAP_LOAD(2);   WAITV(8); TAP_FMA(0);
    TAP_LOAD(3);   WAITV(8); TAP_FMA(1);
    TAP_LOAD(4);   WAITV(8); TAP_FMA(2);
    TAP_LOAD(5);   WAITV(8); TAP_FMA(3);
    TAP_LOAD(6);   WAITV(8); TAP_FMA(4);
    TAP_LOAD(7);   WAITV(8); TAP_FMA(5);
    TAP_LOAD(8);   WAITV(8); TAP_FMA(6);
    WAITV(4); TAP_FMA(7);
    WAITV(0); TAP_FMA(8);

#undef GLOAD
#undef WAITV
#undef TAP_LOAD
#undef TAP_FMA

    float* outp = out + (size_t)(b*CC + g*GC + q*4) * HWSZ + pixel;
    outp[0*HWSZ] = acc0;
    outp[1*HWSZ] = acc1;
    outp[2*HWSZ] = acc2;
    outp[3*HWSZ] = acc3;
}

// ---------- Fallback: direct planar kernel (if ws too small) ----------
__global__ __launch_bounds__(256) void misc_filter_direct(
    const float* __restrict__ img,
    const float* __restrict__ kv,
    const float* __restrict__ kh,
    const float* __restrict__ off,
    const float* __restrict__ wgt,
    float* __restrict__ out)
{
    int phys = blockIdx.x;
    int logical = (phys & 7) * (NBLK_RP / 8) + (phys >> 3);
    int y  = logical & (HH - 1);
    int bg = logical >> 8;
    int g  = bg & (GG - 1);
    int b  = bg >> 2;
    int x  = threadIdx.x;

    const float* imgp = img + (size_t)(b*CC + g*GC) * HWSZ;
    int pix = y*WW + x;
    const float* offp = off + (size_t)(b*GG*PP*2 + g*PP*2) * HWSZ + pix;
    const float* wgtp = wgt + (size_t)(b*GG*PP   + g*PP  ) * HWSZ + pix;
    const float* khp  = kh  + (size_t)(b*GG*KK   + g*KK  ) * HWSZ + pix;
    const float* kvp  = kv  + (size_t)(b*KK) * HWSZ + pix;

    float khr[KK], kvr[KK];
#pragma unroll
    for (int i = 0; i < KK; ++i) { khr[i] = khp[i*HWSZ]; kvr[i] = kvp[i*HWSZ]; }
    float acc[GC];
#pragma unroll
    for (int c = 0; c < GC; ++c) acc[c] = 0.f;

#pragma unroll
    for (int p = 0; p < PP; ++p) {
        const int kx = p / KK, ky = p % KK;
        float ox = offp[(2*p  )*HWSZ];
        float oy = offp[(2*p+1)*HWSZ];
        float wp = wgtp[p*HWSZ] * khr[kx] * kvr[ky];
        float ux = (float)(x + kx - 1) + ox;
        float uy = (float)(y + ky - 1) + oy;
        float fx = floorf(ux), fy = floorf(uy);
        float wx = ux - fx,    wy = uy - fy;
        int x0 = (int)fx, y0 = (int)fy;
        int x1 = x0 + 1,  y1 = y0 + 1;
        bool vx0 = (unsigned)x0 < (unsigned)WW;
        bool vx1 = (unsigned)x1 < (unsigned)WW;
        bool vy0 = (unsigned)y0 < (unsigned)HH;
        bool vy1 = (unsigned)y1 < (unsigned)HH;
        float w00 = (1.f-wx)*(1.f-wy)*wp; if (!(vx0 && vy0)) w00 = 0.f;
        float w01 =      wx *(1.f-wy)*wp; if (!(vx1 && vy0)) w01 = 0.f;
        float w10 = (1.f-wx)*     wy *wp; if (!(vx0 && vy1)) w10 = 0.f;
        float w11 =      wx *     wy *wp; if (!(vx1 && vy1)) w11 = 0.f;
        int x0c = min(max(x0, 0), WW-1), x1c = min(max(x1, 0), WW-1);
        int y0c = min(max(y0, 0), HH-1), y1c = min(max(y1, 0), HH-1);
        int i00 = y0c*WW + x0c, i01 = y0c*WW + x1c;
        int i10 = y1c*WW + x0c, i11 = y1c*WW + x1c;
#pragma unroll
        for (int c = 0; c < GC; ++c) {
            const float* pl = imgp + c*HWSZ;
            acc[c] = fmaf(w00, pl[i00], acc[c]);
            acc[c] = fmaf(w01, pl[i01], acc[c]);
            acc[c] = fmaf(w10, pl[i10], acc[c]);
            acc[c] = fmaf(w11, pl[i11], acc[c]);
        }
    }
    float* outp = out + (size_t)(b*CC + g*GC) * HWSZ + pix;
#pragma unroll
    for (int c = 0; c < GC; ++c) outp[c*HWSZ] = acc[c];
}

extern "C" void kernel_launch(void* const* d_in, const int* in_sizes, int n_in,
                              void* d_out, int out_size, void* d_ws, size_t ws_size,
                              hipStream_t stream) {
    const float* img = (const float*)d_in[0];
    const float* kv  = (const float*)d_in[1];
    const float* kh  = (const float*)d_in[2];
    const float* off = (const float*)d_in[3];
    const float* wgt = (const float*)d_in[4];
    float* out = (float*)d_out;

    const size_t need = (size_t)NBG * HWSZ * GC * sizeof(float);  // 33.5 MB
    if (ws_size >= need) {
        float* pk = (float*)d_ws;
        repack_kernel<<<dim3(NBLK_RP), dim3(WW), 0, stream>>>(img, pk);
        misc_filter_coop<<<dim3(NBLK_MAIN), dim3(256), 0, stream>>>(pk, kv, kh, off, wgt, out);
    } else {
        misc_filter_direct<<<dim3(NBLK_RP), dim3(WW), 0, stream>>>(img, kv, kh, off, wgt, out);
    }
}